// Round 6
// baseline (34391.043 us; speedup 1.0000x reference)
//
#include <hip/hip_runtime.h>

// ---------------------------------------------------------------------------
// 3-layer LayerNorm-GRU (haste style), B=32 T=512 IN=128 H=1024 OUT=80
// Round 6: ZERO-FENCE sync. R2/R3/R5 all hit ~19.5us/step with three
// different mechanisms -> the shared cost is agent __threadfence
// (buffer_wbl2/buffer_inv) + post-inv L3 refetch, not arrival handling.
// Fix: all exchanged data (h, pstat, statfin, flags) uses relaxed
// AGENT-scope atomics (sc1, coherence-point direct) -> no fences at all.
// Producer ordering: __syncthreads drains per-wave vmcnt before s_barrier,
// so flag stores follow completed data stores (same property R2-R5 relied
// on). Dedicated aggregator block (grid=129): polls 128 flags, reduces
// pstat 128->1 itself (kills the 4MB/step all-to-all), relays epochs.
// ---------------------------------------------------------------------------

typedef float    f32x4 __attribute__((ext_vector_type(4)));
typedef _Float16 f16x8 __attribute__((ext_vector_type(8)));

#define HH      1024
#define TT      512
#define BBATCH  32
#define H3      3072
#define MROWS   16384      // B*T
#define NBLK_R  128        // compute blocks (block NBLK_R = aggregator)
#define HPB     8          // h-indices per recurrence block
#define COLS    24         // 3*HPB columns of R per block
#define LN_EPS  1e-5f

// ctrl region word offsets (128B line separation for flag lines)
#define W_SEQA  0          // 128 lines * 32 words
#define W_SEQB  4096
#define W_EPA   8192       // 8 lines
#define W_EPB   8448
#define W_SFIN  9216       // 64 floats (statfin)

// workspace layout (bytes)
#define OFF_CTRL   0u
#define OFF_PSTAT  40960u             // pstat[128][64] f32 = 32 KB (ends 73728)
#define OFF_H      73728u             // h packed 2xfp16 per word [32][512] = 64 KB
#define OFF_HF     139264u            // h fp32 [32][1024] = 128 KB (ends 270336)
#define CTRL_BYTES 270336u            // memset region
#define OFF_WLB    327680u            // Wlin^T fp16 [80][1024]  = 160 KB
#define OFF_WB     524288u            // W^T fp16 [3072][K<=1024] = 6 MB
#define OFF_XBF    (8ull<<20)         // x fp16 [16384][128]     = 4 MB
#define OFF_WX     (16ull<<20)        // wx fp16 [16384][3072]   = 96 MB
#define OFF_HSA    (112ull<<20)       // hs fp16 [16384][1024]   = 32 MB
#define OFF_HSB    (144ull<<20)       // hs fp16 [16384][1024]   = 32 MB  (end 176 MB)

#define ALOAD(p)    __hip_atomic_load((p),  __ATOMIC_RELAXED, __HIP_MEMORY_SCOPE_AGENT)
#define ASTORE(p,v) __hip_atomic_store((p), (v), __ATOMIC_RELAXED, __HIP_MEMORY_SCOPE_AGENT)

// load 8 packed fp16 (4 words) coherently from hglob
__device__ __forceinline__ f16x8 ldh(const unsigned* w) {
  union { unsigned u[4]; f16x8 v; } r;
#pragma unroll
  for (int i = 0; i < 4; ++i) r.u[i] = ALOAD(w + i);
  return r.v;
}

// aggregator: wave-parallel poll of 128 flag lines (2 per lane)
__device__ __forceinline__ void agg_wait(const unsigned* seq, unsigned tgt) {
  const unsigned* p0 = seq + threadIdx.x * 32;
  const unsigned* p1 = seq + (threadIdx.x + 64) * 32;
  int spins = 0;
  for (;;) {
    const unsigned a = ALOAD(p0);
    const unsigned b = ALOAD(p1);
    if (__all((a >= tgt) && (b >= tgt))) break;
    __builtin_amdgcn_s_sleep(1);
    if (++spins > (1 << 24)) break;   // safety: wrong answer, not hang
  }
}

// consumer: single-lane poll of own bucket epoch line
__device__ __forceinline__ void cons_wait(const unsigned* ep, unsigned tgt) {
  int spins = 0;
  while (ALOAD(ep) < tgt) {
    __builtin_amdgcn_s_sleep(1);
    if (++spins > (1 << 24)) break;
  }
}

// ---------------------------------------------------------------------------
// init: x fp32 -> fp16 ; Wlin [1024][80] -> Wlb^T fp16 [80][1024]
__global__ __launch_bounds__(256, 1) void k_init(
    const float* __restrict__ x, _Float16* __restrict__ xb,
    const float* __restrict__ Wlin, _Float16* __restrict__ Wlb)
{
  const size_t stride = (size_t)gridDim.x * 256;
  for (size_t i = (size_t)blockIdx.x * 256 + threadIdx.x; i < (size_t)MROWS * 128; i += stride)
    xb[i] = (_Float16)x[i];
  for (size_t i = (size_t)blockIdx.x * 256 + threadIdx.x; i < 80u * 1024u; i += stride) {
    const size_t n = i >> 10, k = i & 1023u;
    Wlb[i] = (_Float16)Wlin[k * 80 + n];
  }
}

// W fp32 [K][3072] -> Wb fp16 [3072][K] (n-major for B-fragments)
__global__ __launch_bounds__(256, 1) void k_convW(
    const float* __restrict__ W, _Float16* __restrict__ Wb, const int K)
{
  const int n = blockIdx.x;
  for (int k = threadIdx.x; k < K; k += 256)
    Wb[(size_t)n * K + k] = (_Float16)W[(size_t)k * H3 + n];
}

// Cw[16384][3072] (fp16, raw pre-LN) = A[16384][K] @ W[K][3072]
__global__ __launch_bounds__(256, 1) void k_gemm(
    const _Float16* __restrict__ A,
    const _Float16* __restrict__ Bw,   // [3072][K]
    _Float16* __restrict__ Cw,
    const int K)
{
  __shared__ _Float16 Bs[64][40];
  const int tid = threadIdx.x;
  const int lane = tid & 63, wv = tid >> 6;
  const int l15 = lane & 15, quad = lane >> 4;
  const int tilem = blockIdx.x / 48, tilen = blockIdx.x % 48;
  const int mbase = tilem * 64 + wv * 16;
  const size_t nbase = (size_t)tilen * 64;
  f32x4 acc[4] = {{0.f,0.f,0.f,0.f},{0.f,0.f,0.f,0.f},{0.f,0.f,0.f,0.f},{0.f,0.f,0.f,0.f}};
  const _Float16* arow = A + (size_t)(mbase + l15) * K + quad * 8;
  const int sn = tid >> 2, sk = (tid & 3) * 8;
  const _Float16* bsrc = Bw + (nbase + sn) * K + sk;
  for (int kc = 0; kc < K; kc += 32) {
    __syncthreads();
    *(f16x8*)(&Bs[sn][sk]) = *(const f16x8*)(bsrc + kc);
    __syncthreads();
    const f16x8 af = *(const f16x8*)(arow + kc);
#pragma unroll
    for (int nt = 0; nt < 4; ++nt) {
      const f16x8 bv = *(const f16x8*)(&Bs[nt * 16 + l15][quad * 8]);
      acc[nt] = __builtin_amdgcn_mfma_f32_16x16x32_f16(af, bv, acc[nt], 0, 0, 0);
    }
  }
#pragma unroll
  for (int nt = 0; nt < 4; ++nt)
#pragma unroll
    for (int j = 0; j < 4; ++j)
      Cw[(size_t)(mbase + quad * 4 + j) * H3 + nbase + nt * 16 + l15] = (_Float16)acc[nt][j];
}

// in-place LayerNorm * gw over rows of wx (3072 cols), one row per wave
__global__ __launch_bounds__(256, 1) void k_ln(
    _Float16* __restrict__ wxp, const float* __restrict__ gw)
{
  const int wv = threadIdx.x >> 6, lane = threadIdx.x & 63;
  const size_t row = (size_t)blockIdx.x * 4 + wv;
  _Float16* p = wxp + row * H3 + lane * 8;
  float vals[48];
  float s = 0.f, q = 0.f;
#pragma unroll
  for (int c = 0; c < 6; ++c) {
    const f16x8 v = *(const f16x8*)(p + c * 512);
#pragma unroll
    for (int j = 0; j < 8; ++j) {
      const float f = (float)v[j];
      vals[c * 8 + j] = f; s += f; q += f * f;
    }
  }
#pragma unroll
  for (int m = 1; m < 64; m <<= 1) { s += __shfl_xor(s, m); q += __shfl_xor(q, m); }
  const float mean = s * (1.f / H3);
  const float var  = q * (1.f / H3) - mean * mean;
  const float inv  = rsqrtf(var + LN_EPS);
#pragma unroll
  for (int c = 0; c < 6; ++c) {
    f16x8 o;
#pragma unroll
    for (int j = 0; j < 8; ++j)
      o[j] = (_Float16)((vals[c * 8 + j] - mean) * inv * gw[c * 512 + lane * 8 + j]);
    *(f16x8*)(p + c * 512) = o;
  }
}

// ---------------------------------------------------------------------------
// recurrence: 512 steps, 128 compute blocks + 1 aggregator block, no fences
__global__ __launch_bounds__(256, 1) void k_recur(
    const float* __restrict__ R, const float* __restrict__ bx,
    const float* __restrict__ br, const float* __restrict__ gr,
    const _Float16* __restrict__ wx,
    _Float16* __restrict__ hs_out,
    unsigned* __restrict__ hglob,     // packed 2xfp16 [32][512]
    float* __restrict__ hf32,
    float* __restrict__ pstat,        // [128][64] partial stats
    unsigned* __restrict__ ctrl,
    float* __restrict__ sfin,         // [64] reduced stats
    const unsigned abase,             // l*TT
    const unsigned hbase)             // l*(TT+1)
{
  const int tid = threadIdx.x;
  const int blk = blockIdx.x;
  unsigned* seqA = ctrl + W_SEQA;
  unsigned* seqB = ctrl + W_SEQB;
  unsigned* epA  = ctrl + W_EPA;
  unsigned* epB  = ctrl + W_EPB;

  // ---------------- aggregator block ----------------
  if (blk == NBLK_R) {
    if (tid >= 64) return;            // wave 0 only; no __syncthreads on this path
    for (int t = 0; t < TT; ++t) {
      // relay h flags -> epoch B
      agg_wait(seqB, hbase + (unsigned)t + 1u);
      if (tid < 8) ASTORE(&epB[tid * 32], hbase + (unsigned)t + 1u);
      // wait stats flags, reduce 128 partials -> statfin, release epoch A
      agg_wait(seqA, abase + (unsigned)t + 1u);
      float s = 0.f;
      const float* pp = pstat + tid;
#pragma unroll 16
      for (int b2 = 0; b2 < NBLK_R; ++b2) s += ALOAD(pp + b2 * 64);
      ASTORE(&sfin[tid], s);
      asm volatile("s_waitcnt vmcnt(0)" ::: "memory");   // sfin visible before epoch
      if (tid < 8) ASTORE(&epA[tid * 32], abase + (unsigned)t + 1u);
    }
    return;
  }

  // ---------------- compute blocks ----------------
  __shared__ _Float16 Rs[COLS][HH + 8];
  __shared__ float rhbuf[BBATCH][COLS];
  __shared__ float statbuf[BBATCH][2][2];
  __shared__ float statfin_s[64];

  const int lane = tid & 63;
  const int wv   = tid >> 6;
  const int mhalf = wv >> 1;      // which 16 batch rows
  const int ntile = wv & 1;       // which 16-col tile of the 24 cols
  const int l15  = lane & 15;
  const int quad = lane >> 4;

  // load R slice (cols {i, H+i, 2H+i} for i in [blk*8, blk*8+8)), fp32->fp16
  for (int n = 0; n < COLS; ++n) {
    const int gc = (n >> 3) * HH + blk * HPB + (n & 7);
    for (int k = tid; k < HH; k += 256)
      Rs[n][k] = (_Float16)R[(size_t)k * H3 + gc];
  }

  // per-thread gate ownership: (batch row, h-index)
  const int b_row = tid >> 3;
  const int jj    = tid & 7;
  const int gi    = blk * HPB + jj;
  const float bxz = bx[gi], bxr = bx[HH + gi], bxg = bx[2 * HH + gi];
  const float brz = br[gi], brr = br[HH + gi], brg = br[2 * HH + gi];
  const float grz = gr[gi], grr = gr[HH + gi], grg = gr[2 * HH + gi];
  float hloc = hf32[b_row * HH + gi];

  // initial coherent publish of own h slice (packed words), flag hbase+1
  {
    union { _Float16 f; unsigned short s; } hc; hc.f = (_Float16)hloc;
    const unsigned short mybits = hc.s;
    const unsigned short pbits  = (unsigned short)__shfl_xor((int)mybits, 1);
    if ((jj & 1) == 0) {
      const unsigned w = (unsigned)mybits | ((unsigned)pbits << 16);
      ASTORE(&hglob[b_row * 512 + blk * 4 + (jj >> 1)], w);
    }
  }
  __syncthreads();                 // per-wave vmcnt(0) drained before barrier
  if (tid == 0) {
    asm volatile("s_waitcnt vmcnt(0)" ::: "memory");
    ASTORE(&seqB[blk * 32], hbase + 1u);
  }

  const unsigned* hrowW = hglob + (size_t)(mhalf * 16 + l15) * 512 + quad * 4;
  int nloc = ntile * 16 + l15; if (nloc >= COLS) nloc = COLS - 1;   // clamp pad lanes
  const bool valid = (ntile == 0) | (l15 < 8);
  const unsigned* myEpA = epA + (blk & 7) * 32;
  const unsigned* myEpB = epB + (blk & 7) * 32;

  for (int t = 0; t < TT; ++t) {
    if (tid == 0) cons_wait(myEpB, hbase + (unsigned)t + 1u);  // h(t) visible
    __syncthreads();

    // ---- phase 1: rh chunk = h @ Rslice; A via coherent packed loads
    f32x4 acc0 = {0.f,0.f,0.f,0.f}, acc1 = {0.f,0.f,0.f,0.f};
#pragma unroll
    for (int ks = 0; ks < 32; ks += 2) {
      const f16x8 a0 = ldh(hrowW + ks * 16);
      const f16x8 b0 = *(const f16x8*)(&Rs[nloc][ks * 32 + quad * 8]);
      acc0 = __builtin_amdgcn_mfma_f32_16x16x32_f16(a0, b0, acc0, 0, 0, 0);
      const f16x8 a1 = ldh(hrowW + ks * 16 + 16);
      const f16x8 b1 = *(const f16x8*)(&Rs[nloc][ks * 32 + 32 + quad * 8]);
      acc1 = __builtin_amdgcn_mfma_f32_16x16x32_f16(a1, b1, acc1, 0, 0, 0);
    }
    const f32x4 c = acc0 + acc1;

    // per-row partial LN stats over this block's 24 cols + stash rh values
#pragma unroll
    for (int j = 0; j < 4; ++j) {
      const float v = valid ? c[j] : 0.f;
      if (valid) rhbuf[mhalf * 16 + quad * 4 + j][ntile * 16 + l15] = v;
      float s = v, q = v * v;
      s += __shfl_xor(s, 1); q += __shfl_xor(q, 1);
      s += __shfl_xor(s, 2); q += __shfl_xor(q, 2);
      s += __shfl_xor(s, 4); q += __shfl_xor(q, 4);
      s += __shfl_xor(s, 8); q += __shfl_xor(q, 8);
      if (l15 == 0) {
        statbuf[mhalf * 16 + quad * 4 + j][ntile][0] = s;
        statbuf[mhalf * 16 + quad * 4 + j][ntile][1] = q;
      }
    }
    __syncthreads();
    if (tid < 64) {
      const int row = tid >> 1, st = tid & 1;
      ASTORE(&pstat[blk * 64 + tid], statbuf[row][0][st] + statbuf[row][1][st]);
    }
    __syncthreads();                 // drain pstat stores (wave 0)
    if (tid == 0) {
      asm volatile("s_waitcnt vmcnt(0)" ::: "memory");
      ASTORE(&seqA[blk * 32], abase + (unsigned)t + 1u);
    }

    // prefetch phase-2 operands while stats aggregate (wx static, rhbuf local)
    const float rzraw = rhbuf[b_row][jj];
    const float rrraw = rhbuf[b_row][8 + jj];
    const float rgraw = rhbuf[b_row][16 + jj];
    const _Float16* wrow = wx + (size_t)(b_row * TT + t) * H3;
    const float wz = (float)wrow[gi];
    const float wr = (float)wrow[HH + gi];
    const float wg = (float)wrow[2 * HH + gi];

    if (tid == 0) cons_wait(myEpA, abase + (unsigned)t + 1u);  // statfin ready
    __syncthreads();
    if (tid < 64) statfin_s[tid] = ALOAD(&sfin[tid]);
    __syncthreads();

    // ---- phase 2: finalize LN, gates, h update
    const float mean = statfin_s[b_row * 2 + 0] * (1.f / H3);
    const float var  = statfin_s[b_row * 2 + 1] * (1.f / H3) - mean * mean;
    const float inv  = rsqrtf(var + LN_EPS);
    const float rz = (rzraw - mean) * inv * grz;
    const float rr = (rrraw - mean) * inv * grr;
    const float rg = (rgraw - mean) * inv * grg;
    const float zg    = 1.f / (1.f + __expf(-(wz + bxz + rz + brz)));
    const float rgate = 1.f / (1.f + __expf(-(wr + bxr + rr + brr)));
    const float gg    = tanhf(wg + bxg + rgate * (rg + brg));
    const float hn = zg * hloc + (1.f - zg) * gg;
    hloc = hn;
    union { _Float16 f; unsigned short s; } hc; hc.f = (_Float16)hn;
    const unsigned short mybits = hc.s;
    const unsigned short pbits  = (unsigned short)__shfl_xor((int)mybits, 1);
    if ((jj & 1) == 0) {
      const unsigned w = (unsigned)mybits | ((unsigned)pbits << 16);
      ASTORE(&hglob[b_row * 512 + blk * 4 + (jj >> 1)], w);
    }
    hs_out[(size_t)(b_row * TT + t) * HH + gi] = hc.f;
    __syncthreads();                 // drain h stores (all waves, pre-barrier vmcnt)
    if (tid == 0) {
      asm volatile("s_waitcnt vmcnt(0)" ::: "memory");
      ASTORE(&seqB[blk * 32], hbase + (unsigned)t + 2u);
    }
  }
  hf32[b_row * HH + gi] = hloc;   // fp32 handoff to next layer
}

// ---------------------------------------------------------------------------
// out[16384][80] = tanh(hs @ Wlin + blin)
__global__ __launch_bounds__(256, 1) void k_proj(
    const _Float16* __restrict__ hs,
    const _Float16* __restrict__ Wlb,   // [80][1024] fp16
    const float* __restrict__ blin,
    float* __restrict__ out)
{
  const int tid = threadIdx.x, lane = tid & 63, wv = tid >> 6;
  const int l15 = lane & 15, quad = lane >> 4;
  const int mbase = blockIdx.x * 64 + wv * 16;
  f32x4 acc[5] = {{0.f,0.f,0.f,0.f},{0.f,0.f,0.f,0.f},{0.f,0.f,0.f,0.f},
                  {0.f,0.f,0.f,0.f},{0.f,0.f,0.f,0.f}};
  const _Float16* arow = hs + (size_t)(mbase + l15) * HH + quad * 8;
  for (int kc = 0; kc < HH; kc += 32) {
    const f16x8 af = *(const f16x8*)(arow + kc);
#pragma unroll
    for (int nt = 0; nt < 5; ++nt) {
      const f16x8 bv = *(const f16x8*)(Wlb + (size_t)(nt * 16 + l15) * HH + kc + quad * 8);
      acc[nt] = __builtin_amdgcn_mfma_f32_16x16x32_f16(af, bv, acc[nt], 0, 0, 0);
    }
  }
#pragma unroll
  for (int nt = 0; nt < 5; ++nt)
#pragma unroll
    for (int j = 0; j < 4; ++j) {
      const int col = nt * 16 + l15;
      out[(size_t)(mbase + quad * 4 + j) * 80 + col] = tanhf(acc[nt][j] + blin[col]);
    }
}

// ---------------------------------------------------------------------------
extern "C" void kernel_launch(void* const* d_in, const int* in_sizes, int n_in,
                              void* d_out, int out_size, void* d_ws, size_t ws_size,
                              hipStream_t stream)
{
  const float* x    = (const float*)d_in[0];
  const float* W0   = (const float*)d_in[1];
  const float* R0   = (const float*)d_in[2];
  const float* bx0  = (const float*)d_in[3];
  const float* br0  = (const float*)d_in[4];
  const float* gw0  = (const float*)d_in[5];
  const float* gr0  = (const float*)d_in[6];
  const float* Wk   = (const float*)d_in[7];
  const float* Rk   = (const float*)d_in[8];
  const float* bxk  = (const float*)d_in[9];
  const float* brk  = (const float*)d_in[10];
  const float* gwk  = (const float*)d_in[11];
  const float* grk  = (const float*)d_in[12];
  const float* Wlin = (const float*)d_in[13];
  const float* blin = (const float*)d_in[14];

  char* ws = (char*)d_ws;
  unsigned*  ctrl   = (unsigned*)(ws + OFF_CTRL);
  float*     sfin   = (float*)(ws + OFF_CTRL + W_SFIN * 4u);
  float*     pstat  = (float*)(ws + OFF_PSTAT);
  unsigned*  hglob  = (unsigned*)(ws + OFF_H);
  float*     hf32   = (float*)(ws + OFF_HF);
  _Float16*  Wlb    = (_Float16*)(ws + OFF_WLB);
  _Float16*  Wb     = (_Float16*)(ws + OFF_WB);
  _Float16*  xb     = (_Float16*)(ws + OFF_XBF);
  _Float16*  wx     = (_Float16*)(ws + OFF_WX);
  _Float16*  hsA    = (_Float16*)(ws + OFF_HSA);
  _Float16*  hsB    = (_Float16*)(ws + OFF_HSB);

  hipMemsetAsync(d_ws, 0, CTRL_BYTES, stream);   // flags, epochs, pstat, h state

  k_init<<<2048, 256, 0, stream>>>(x, xb, Wlin, Wlb);

  for (int l = 0; l < 3; ++l) {
    const int K = l ? HH : 128;
    const float* Wl  = l ? (Wk  + (size_t)(l - 1) * HH * H3) : W0;
    const float* Rl  = l ? (Rk  + (size_t)(l - 1) * HH * H3) : R0;
    const float* bxl = l ? (bxk + (size_t)(l - 1) * H3) : bx0;
    const float* brl = l ? (brk + (size_t)(l - 1) * H3) : br0;
    const float* gwl = l ? (gwk + (size_t)(l - 1) * H3) : gw0;
    const float* grl = l ? (grk + (size_t)(l - 1) * H3) : gr0;
    const _Float16* Ain = (l == 0) ? xb : ((l == 1) ? hsA : hsB);
    _Float16* hs_out = (l == 1) ? hsB : hsA;

    k_convW<<<H3, 256, 0, stream>>>(Wl, Wb, K);
    k_gemm<<<12288, 256, 0, stream>>>(Ain, Wb, wx, K);
    k_ln<<<4096, 256, 0, stream>>>(wx, gwl);
    k_recur<<<NBLK_R + 1, 256, 0, stream>>>(Rl, bxl, brl, grl, wx, hs_out,
                                            hglob, hf32, pstat, ctrl, sfin,
                                            (unsigned)l * (unsigned)TT,
                                            (unsigned)l * (TT + 1u));
  }
  k_proj<<<256, 256, 0, stream>>>(hsA, Wlb, blin, (float*)d_out);
}

// Round 7
// 23761.064 us; speedup vs baseline: 1.4474x; 1.4474x over previous
//
#include <hip/hip_runtime.h>

// ---------------------------------------------------------------------------
// 3-layer LayerNorm-GRU (haste style), B=32 T=512 IN=128 H=1024 OUT=80
// Round 7: hybrid coherence.
//   R2-R6 lessons: arrival mechanism ~free; __threadfence (wbl2+inv) is the
//   cost; sc1 direct is cheap for small words, ruinous for bulk (R6).
//   -> producers: sc1 stores ONLY for h slice (16 dw) + pstat (64 dw) + flags,
//      wave-local s_waitcnt vmcnt(0), NO release fences (hs_out/hf32 stay
//      cached; kernel-boundary coherence covers them).
//   -> consumers: ONE acquire-only fence (inv, no wbl2) per step gates cached
//      f16x8 vector h loads (L2-amortized across the XCD); sfin via 64 sc1
//      dwords, no second fence.
//   -> aggregator block (grid=129), two independent waves: wave0 relays
//      h flags -> epochB; wave1 reduces pstat 128->1 -> sfin -> epochA.
// ---------------------------------------------------------------------------

typedef float    f32x4 __attribute__((ext_vector_type(4)));
typedef _Float16 f16x8 __attribute__((ext_vector_type(8)));

#define HH      1024
#define TT      512
#define BBATCH  32
#define H3      3072
#define MROWS   16384      // B*T
#define NBLK_R  128        // compute blocks (block NBLK_R = aggregator)
#define HPB     8          // h-indices per recurrence block
#define COLS    24         // 3*HPB columns of R per block
#define LN_EPS  1e-5f

// ctrl region word offsets (128B line separation for flag lines)
#define W_SEQA  0          // 128 lines * 32 words
#define W_SEQB  4096
#define W_EPA   8192       // 8 lines
#define W_EPB   8448
#define W_SFIN  9216       // 64 floats (statfin)

// workspace layout (bytes)
#define OFF_CTRL   0u
#define OFF_PSTAT  40960u             // pstat[128][64] f32 = 32 KB (ends 73728)
#define OFF_H      73728u             // h fp16 [32][1024] = 64 KB
#define OFF_HF     139264u            // h fp32 [32][1024] = 128 KB (ends 270336)
#define CTRL_BYTES 270336u            // memset region
#define OFF_WLB    327680u            // Wlin^T fp16 [80][1024]  = 160 KB
#define OFF_WB     524288u            // W^T fp16 [3072][K<=1024] = 6 MB
#define OFF_XBF    (8ull<<20)         // x fp16 [16384][128]     = 4 MB
#define OFF_WX     (16ull<<20)        // wx fp16 [16384][3072]   = 96 MB
#define OFF_HSA    (112ull<<20)       // hs fp16 [16384][1024]   = 32 MB
#define OFF_HSB    (144ull<<20)       // hs fp16 [16384][1024]   = 32 MB  (end 176 MB)

#define ALOAD(p)    __hip_atomic_load((p),  __ATOMIC_RELAXED, __HIP_MEMORY_SCOPE_AGENT)
#define ASTORE(p,v) __hip_atomic_store((p), (v), __ATOMIC_RELAXED, __HIP_MEMORY_SCOPE_AGENT)

// aggregator wave: parallel poll of 128 flag lines (2 per lane)
__device__ __forceinline__ void agg_wait(const unsigned* seq, unsigned tgt, int lane) {
  const unsigned* p0 = seq + lane * 32;
  const unsigned* p1 = seq + (lane + 64) * 32;
  int spins = 0;
  for (;;) {
    const unsigned a = ALOAD(p0);
    const unsigned b = ALOAD(p1);
    if (__all((a >= tgt) && (b >= tgt))) break;
    __builtin_amdgcn_s_sleep(1);
    if (++spins > (1 << 24)) break;   // safety: wrong answer, not hang
  }
}

// consumer: single-lane poll of own bucket epoch line
__device__ __forceinline__ void cons_wait(const unsigned* ep, unsigned tgt) {
  int spins = 0;
  while (ALOAD(ep) < tgt) {
    __builtin_amdgcn_s_sleep(1);
    if (++spins > (1 << 24)) break;
  }
}

// ---------------------------------------------------------------------------
// init: x fp32 -> fp16 ; Wlin [1024][80] -> Wlb^T fp16 [80][1024]
__global__ __launch_bounds__(256, 1) void k_init(
    const float* __restrict__ x, _Float16* __restrict__ xb,
    const float* __restrict__ Wlin, _Float16* __restrict__ Wlb)
{
  const size_t stride = (size_t)gridDim.x * 256;
  for (size_t i = (size_t)blockIdx.x * 256 + threadIdx.x; i < (size_t)MROWS * 128; i += stride)
    xb[i] = (_Float16)x[i];
  for (size_t i = (size_t)blockIdx.x * 256 + threadIdx.x; i < 80u * 1024u; i += stride) {
    const size_t n = i >> 10, k = i & 1023u;
    Wlb[i] = (_Float16)Wlin[k * 80 + n];
  }
}

// W fp32 [K][3072] -> Wb fp16 [3072][K] (n-major for B-fragments)
__global__ __launch_bounds__(256, 1) void k_convW(
    const float* __restrict__ W, _Float16* __restrict__ Wb, const int K)
{
  const int n = blockIdx.x;
  for (int k = threadIdx.x; k < K; k += 256)
    Wb[(size_t)n * K + k] = (_Float16)W[(size_t)k * H3 + n];
}

// Cw[16384][3072] (fp16, raw pre-LN) = A[16384][K] @ W[K][3072]
__global__ __launch_bounds__(256, 1) void k_gemm(
    const _Float16* __restrict__ A,
    const _Float16* __restrict__ Bw,   // [3072][K]
    _Float16* __restrict__ Cw,
    const int K)
{
  __shared__ _Float16 Bs[64][40];
  const int tid = threadIdx.x;
  const int lane = tid & 63, wv = tid >> 6;
  const int l15 = lane & 15, quad = lane >> 4;
  const int tilem = blockIdx.x / 48, tilen = blockIdx.x % 48;
  const int mbase = tilem * 64 + wv * 16;
  const size_t nbase = (size_t)tilen * 64;
  f32x4 acc[4] = {{0.f,0.f,0.f,0.f},{0.f,0.f,0.f,0.f},{0.f,0.f,0.f,0.f},{0.f,0.f,0.f,0.f}};
  const _Float16* arow = A + (size_t)(mbase + l15) * K + quad * 8;
  const int sn = tid >> 2, sk = (tid & 3) * 8;
  const _Float16* bsrc = Bw + (nbase + sn) * K + sk;
  for (int kc = 0; kc < K; kc += 32) {
    __syncthreads();
    *(f16x8*)(&Bs[sn][sk]) = *(const f16x8*)(bsrc + kc);
    __syncthreads();
    const f16x8 af = *(const f16x8*)(arow + kc);
#pragma unroll
    for (int nt = 0; nt < 4; ++nt) {
      const f16x8 bv = *(const f16x8*)(&Bs[nt * 16 + l15][quad * 8]);
      acc[nt] = __builtin_amdgcn_mfma_f32_16x16x32_f16(af, bv, acc[nt], 0, 0, 0);
    }
  }
#pragma unroll
  for (int nt = 0; nt < 4; ++nt)
#pragma unroll
    for (int j = 0; j < 4; ++j)
      Cw[(size_t)(mbase + quad * 4 + j) * H3 + nbase + nt * 16 + l15] = (_Float16)acc[nt][j];
}

// in-place LayerNorm * gw over rows of wx (3072 cols), one row per wave
__global__ __launch_bounds__(256, 1) void k_ln(
    _Float16* __restrict__ wxp, const float* __restrict__ gw)
{
  const int wv = threadIdx.x >> 6, lane = threadIdx.x & 63;
  const size_t row = (size_t)blockIdx.x * 4 + wv;
  _Float16* p = wxp + row * H3 + lane * 8;
  float vals[48];
  float s = 0.f, q = 0.f;
#pragma unroll
  for (int c = 0; c < 6; ++c) {
    const f16x8 v = *(const f16x8*)(p + c * 512);
#pragma unroll
    for (int j = 0; j < 8; ++j) {
      const float f = (float)v[j];
      vals[c * 8 + j] = f; s += f; q += f * f;
    }
  }
#pragma unroll
  for (int m = 1; m < 64; m <<= 1) { s += __shfl_xor(s, m); q += __shfl_xor(q, m); }
  const float mean = s * (1.f / H3);
  const float var  = q * (1.f / H3) - mean * mean;
  const float inv  = rsqrtf(var + LN_EPS);
#pragma unroll
  for (int c = 0; c < 6; ++c) {
    f16x8 o;
#pragma unroll
    for (int j = 0; j < 8; ++j)
      o[j] = (_Float16)((vals[c * 8 + j] - mean) * inv * gw[c * 512 + lane * 8 + j]);
    *(f16x8*)(p + c * 512) = o;
  }
}

// ---------------------------------------------------------------------------
// recurrence: 512 steps, 128 compute blocks + 1 aggregator block
__global__ __launch_bounds__(256, 1) void k_recur(
    const float* __restrict__ R, const float* __restrict__ bx,
    const float* __restrict__ br, const float* __restrict__ gr,
    const _Float16* __restrict__ wx,
    _Float16* __restrict__ hs_out,
    unsigned* __restrict__ hglob,     // h fp16 [32][1024], sc1-stored as u32 pairs
    float* __restrict__ hf32,
    float* __restrict__ pstat,        // [128][64] partial stats
    unsigned* __restrict__ ctrl,
    float* __restrict__ sfin,         // [64] reduced stats
    const unsigned abase,             // l*TT
    const unsigned hbase)             // l*(TT+1)
{
  const int tid = threadIdx.x;
  const int blk = blockIdx.x;
  unsigned* seqA = ctrl + W_SEQA;
  unsigned* seqB = ctrl + W_SEQB;
  unsigned* epA  = ctrl + W_EPA;
  unsigned* epB  = ctrl + W_EPB;

  // ---------------- aggregator block: two independent relay waves ----------
  if (blk == NBLK_R) {
    const int lane = tid & 63;
    const int wv   = tid >> 6;
    if (wv == 0) {              // h-flag relay
      for (int t = 0; t <= TT; ++t) {     // includes initial publish
        agg_wait(seqB, hbase + (unsigned)t + 1u, lane);
        if (lane < 8) ASTORE(&epB[lane * 32], hbase + (unsigned)t + 1u);
      }
    } else if (wv == 1) {       // stats reduce relay
      for (int t = 0; t < TT; ++t) {
        agg_wait(seqA, abase + (unsigned)t + 1u, lane);
        float s = 0.f;
        const float* pp = pstat + lane;
#pragma unroll 16
        for (int b2 = 0; b2 < NBLK_R; ++b2) s += ALOAD(pp + b2 * 64);
        ASTORE(&sfin[lane], s);
        asm volatile("s_waitcnt vmcnt(0)" ::: "memory");  // sfin visible first
        if (lane < 8) ASTORE(&epA[lane * 32], abase + (unsigned)t + 1u);
      }
    }
    return;
  }

  // ---------------- compute blocks ----------------
  __shared__ _Float16 Rs[COLS][HH + 8];
  __shared__ float rhbuf[BBATCH][COLS];
  __shared__ float statbuf[BBATCH][2][2];
  __shared__ float statfin_s[64];

  const int lane = tid & 63;
  const int wv   = tid >> 6;
  const int mhalf = wv >> 1;      // which 16 batch rows
  const int ntile = wv & 1;       // which 16-col tile of the 24 cols
  const int l15  = lane & 15;
  const int quad = lane >> 4;

  // load R slice (cols {i, H+i, 2H+i} for i in [blk*8, blk*8+8)), fp32->fp16
  for (int n = 0; n < COLS; ++n) {
    const int gc = (n >> 3) * HH + blk * HPB + (n & 7);
    for (int k = tid; k < HH; k += 256)
      Rs[n][k] = (_Float16)R[(size_t)k * H3 + gc];
  }

  // per-thread gate ownership: (batch row, h-index)
  const int b_row = tid >> 3;
  const int jj    = tid & 7;
  const int gi    = blk * HPB + jj;
  const float bxz = bx[gi], bxr = bx[HH + gi], bxg = bx[2 * HH + gi];
  const float brz = br[gi], brr = br[HH + gi], brg = br[2 * HH + gi];
  const float grz = gr[gi], grr = gr[HH + gi], grg = gr[2 * HH + gi];
  float hloc = hf32[b_row * HH + gi];

  // initial coherent publish of own h slice (sc1 u32 pairs), flag hbase+1
  {
    union { _Float16 f; unsigned short s; } hc; hc.f = (_Float16)hloc;
    const unsigned short mybits = hc.s;
    const unsigned short pbits  = (unsigned short)__shfl_xor((int)mybits, 1);
    if ((jj & 1) == 0) {
      const unsigned w = (unsigned)mybits | ((unsigned)pbits << 16);
      ASTORE(&hglob[b_row * 512 + blk * 4 + (jj >> 1)], w);
    }
  }
  __syncthreads();                 // all waves' vmcnt drained before barrier
  if (tid == 0) {
    asm volatile("s_waitcnt vmcnt(0)" ::: "memory");
    ASTORE(&seqB[blk * 32], hbase + 1u);
  }

  const _Float16* hread = (const _Float16*)hglob;
  const _Float16* hrow  = hread + (size_t)(mhalf * 16 + l15) * HH + quad * 8;
  int nloc = ntile * 16 + l15; if (nloc >= COLS) nloc = COLS - 1;   // clamp pad lanes
  const bool valid = (ntile == 0) | (l15 < 8);
  const unsigned* myEpA = epA + (blk & 7) * 32;
  const unsigned* myEpB = epB + (blk & 7) * 32;

  for (int t = 0; t < TT; ++t) {
    if (tid == 0) cons_wait(myEpB, hbase + (unsigned)t + 1u);  // h(t) published
    __syncthreads();
    __builtin_amdgcn_fence(__ATOMIC_ACQUIRE, "agent");   // inv only (no wbl2)

    // ---- phase 1: rh chunk = h @ Rslice (cached vector loads, L2-amortized)
    f32x4 acc0 = {0.f,0.f,0.f,0.f}, acc1 = {0.f,0.f,0.f,0.f};
#pragma unroll
    for (int ks = 0; ks < 32; ks += 2) {
      const f16x8 a0 = *(const f16x8*)(hrow + ks * 32);
      const f16x8 b0 = *(const f16x8*)(&Rs[nloc][ks * 32 + quad * 8]);
      acc0 = __builtin_amdgcn_mfma_f32_16x16x32_f16(a0, b0, acc0, 0, 0, 0);
      const f16x8 a1 = *(const f16x8*)(hrow + ks * 32 + 32);
      const f16x8 b1 = *(const f16x8*)(&Rs[nloc][ks * 32 + 32 + quad * 8]);
      acc1 = __builtin_amdgcn_mfma_f32_16x16x32_f16(a1, b1, acc1, 0, 0, 0);
    }
    const f32x4 c = acc0 + acc1;

    // per-row partial LN stats over this block's 24 cols + stash rh values
#pragma unroll
    for (int j = 0; j < 4; ++j) {
      const float v = valid ? c[j] : 0.f;
      if (valid) rhbuf[mhalf * 16 + quad * 4 + j][ntile * 16 + l15] = v;
      float s = v, q = v * v;
      s += __shfl_xor(s, 1); q += __shfl_xor(q, 1);
      s += __shfl_xor(s, 2); q += __shfl_xor(q, 2);
      s += __shfl_xor(s, 4); q += __shfl_xor(q, 4);
      s += __shfl_xor(s, 8); q += __shfl_xor(q, 8);
      if (l15 == 0) {
        statbuf[mhalf * 16 + quad * 4 + j][ntile][0] = s;
        statbuf[mhalf * 16 + quad * 4 + j][ntile][1] = q;
      }
    }
    __syncthreads();
    // publish pstat (wave 0 only; its own s_waitcnt orders flag after data)
    if (tid < 64) {
      const int row = tid >> 1, st = tid & 1;
      ASTORE(&pstat[blk * 64 + tid], statbuf[row][0][st] + statbuf[row][1][st]);
    }
    if (tid == 0) {
      asm volatile("s_waitcnt vmcnt(0)" ::: "memory");
      ASTORE(&seqA[blk * 32], abase + (unsigned)t + 1u);
    }

    // prefetch phase-2 operands while aggregator reduces (wx static, rhbuf LDS)
    const float rzraw = rhbuf[b_row][jj];
    const float rrraw = rhbuf[b_row][8 + jj];
    const float rgraw = rhbuf[b_row][16 + jj];
    const _Float16* wrow = wx + (size_t)(b_row * TT + t) * H3;
    const float wz = (float)wrow[gi];
    const float wr = (float)wrow[HH + gi];
    const float wg = (float)wrow[2 * HH + gi];

    if (tid == 0) cons_wait(myEpA, abase + (unsigned)t + 1u);  // sfin ready
    __syncthreads();
    if (tid < 64) statfin_s[tid] = ALOAD(&sfin[tid]);   // sc1, no fence needed
    __syncthreads();

    // ---- phase 2: finalize LN, gates, h update
    const float mean = statfin_s[b_row * 2 + 0] * (1.f / H3);
    const float var  = statfin_s[b_row * 2 + 1] * (1.f / H3) - mean * mean;
    const float inv  = rsqrtf(var + LN_EPS);
    const float rz = (rzraw - mean) * inv * grz;
    const float rr = (rrraw - mean) * inv * grr;
    const float rg = (rgraw - mean) * inv * grg;
    const float zg    = 1.f / (1.f + __expf(-(wz + bxz + rz + brz)));
    const float rgate = 1.f / (1.f + __expf(-(wr + bxr + rr + brr)));
    const float gg    = tanhf(wg + bxg + rgate * (rg + brg));
    const float hn = zg * hloc + (1.f - zg) * gg;
    hloc = hn;
    union { _Float16 f; unsigned short s; } hc; hc.f = (_Float16)hn;
    const unsigned short mybits = hc.s;
    const unsigned short pbits  = (unsigned short)__shfl_xor((int)mybits, 1);
    if ((jj & 1) == 0) {
      const unsigned w = (unsigned)mybits | ((unsigned)pbits << 16);
      ASTORE(&hglob[b_row * 512 + blk * 4 + (jj >> 1)], w);   // sc1 h publish
    }
    hs_out[(size_t)(b_row * TT + t) * HH + gi] = hc.f;        // cached (kernel-boundary)
    __syncthreads();                 // all waves' vmcnt drained before barrier
    if (tid == 0) {
      asm volatile("s_waitcnt vmcnt(0)" ::: "memory");
      ASTORE(&seqB[blk * 32], hbase + (unsigned)t + 2u);
    }
  }
  hf32[b_row * HH + gi] = hloc;   // fp32 handoff to next layer (cached)
}

// ---------------------------------------------------------------------------
// out[16384][80] = tanh(hs @ Wlin + blin)
__global__ __launch_bounds__(256, 1) void k_proj(
    const _Float16* __restrict__ hs,
    const _Float16* __restrict__ Wlb,   // [80][1024] fp16
    const float* __restrict__ blin,
    float* __restrict__ out)
{
  const int tid = threadIdx.x, lane = tid & 63, wv = tid >> 6;
  const int l15 = lane & 15, quad = lane >> 4;
  const int mbase = blockIdx.x * 64 + wv * 16;
  f32x4 acc[5] = {{0.f,0.f,0.f,0.f},{0.f,0.f,0.f,0.f},{0.f,0.f,0.f,0.f},
                  {0.f,0.f,0.f,0.f},{0.f,0.f,0.f,0.f}};
  const _Float16* arow = hs + (size_t)(mbase + l15) * HH + quad * 8;
  for (int kc = 0; kc < HH; kc += 32) {
    const f16x8 af = *(const f16x8*)(arow + kc);
#pragma unroll
    for (int nt = 0; nt < 5; ++nt) {
      const f16x8 bv = *(const f16x8*)(Wlb + (size_t)(nt * 16 + l15) * HH + kc + quad * 8);
      acc[nt] = __builtin_amdgcn_mfma_f32_16x16x32_f16(af, bv, acc[nt], 0, 0, 0);
    }
  }
#pragma unroll
  for (int nt = 0; nt < 5; ++nt)
#pragma unroll
    for (int j = 0; j < 4; ++j) {
      const int col = nt * 16 + l15;
      out[(size_t)(mbase + quad * 4 + j) * 80 + col] = tanhf(acc[nt][j] + blin[col]);
    }
}

// ---------------------------------------------------------------------------
extern "C" void kernel_launch(void* const* d_in, const int* in_sizes, int n_in,
                              void* d_out, int out_size, void* d_ws, size_t ws_size,
                              hipStream_t stream)
{
  const float* x    = (const float*)d_in[0];
  const float* W0   = (const float*)d_in[1];
  const float* R0   = (const float*)d_in[2];
  const float* bx0  = (const float*)d_in[3];
  const float* br0  = (const float*)d_in[4];
  const float* gw0  = (const float*)d_in[5];
  const float* gr0  = (const float*)d_in[6];
  const float* Wk   = (const float*)d_in[7];
  const float* Rk   = (const float*)d_in[8];
  const float* bxk  = (const float*)d_in[9];
  const float* brk  = (const float*)d_in[10];
  const float* gwk  = (const float*)d_in[11];
  const float* grk  = (const float*)d_in[12];
  const float* Wlin = (const float*)d_in[13];
  const float* blin = (const float*)d_in[14];

  char* ws = (char*)d_ws;
  unsigned*  ctrl   = (unsigned*)(ws + OFF_CTRL);
  float*     sfin   = (float*)(ws + OFF_CTRL + W_SFIN * 4u);
  float*     pstat  = (float*)(ws + OFF_PSTAT);
  unsigned*  hglob  = (unsigned*)(ws + OFF_H);
  float*     hf32   = (float*)(ws + OFF_HF);
  _Float16*  Wlb    = (_Float16*)(ws + OFF_WLB);
  _Float16*  Wb     = (_Float16*)(ws + OFF_WB);
  _Float16*  xb     = (_Float16*)(ws + OFF_XBF);
  _Float16*  wx     = (_Float16*)(ws + OFF_WX);
  _Float16*  hsA    = (_Float16*)(ws + OFF_HSA);
  _Float16*  hsB    = (_Float16*)(ws + OFF_HSB);

  hipMemsetAsync(d_ws, 0, CTRL_BYTES, stream);   // flags, epochs, pstat, h state

  k_init<<<2048, 256, 0, stream>>>(x, xb, Wlin, Wlb);

  for (int l = 0; l < 3; ++l) {
    const int K = l ? HH : 128;
    const float* Wl  = l ? (Wk  + (size_t)(l - 1) * HH * H3) : W0;
    const float* Rl  = l ? (Rk  + (size_t)(l - 1) * HH * H3) : R0;
    const float* bxl = l ? (bxk + (size_t)(l - 1) * H3) : bx0;
    const float* brl = l ? (brk + (size_t)(l - 1) * H3) : br0;
    const float* gwl = l ? (gwk + (size_t)(l - 1) * H3) : gw0;
    const float* grl = l ? (grk + (size_t)(l - 1) * H3) : gr0;
    const _Float16* Ain = (l == 0) ? xb : ((l == 1) ? hsA : hsB);
    _Float16* hs_out = (l == 1) ? hsB : hsA;

    k_convW<<<H3, 256, 0, stream>>>(Wl, Wb, K);
    k_gemm<<<12288, 256, 0, stream>>>(Ain, Wb, wx, K);
    k_ln<<<4096, 256, 0, stream>>>(wx, gwl);
    k_recur<<<NBLK_R + 1, 256, 0, stream>>>(Rl, bxl, brl, grl, wx, hs_out,
                                            hglob, hf32, pstat, ctrl, sfin,
                                            (unsigned)l * (unsigned)TT,
                                            (unsigned)l * (TT + 1u));
  }
  k_proj<<<256, 256, 0, stream>>>(hsA, Wlb, blin, (float*)d_out);
}